// Round 10
// baseline (182.799 us; speedup 1.0000x reference)
//
#include <hip/hip_runtime.h>
#include <hip/hip_bf16.h>
#include <math.h>

#define B_DIM 8
#define C_DIM 32
#define N_DIM 4096
#define NWAVE 16         // waves per block
#define KSL (N_DIM / NWAVE)   // 256 k per wave
#define NCH (KSL / 32)        // 8 chunks per wave

typedef short bf16x8 __attribute__((ext_vector_type(8)));   // 8 bf16 = 4 VGPRs
typedef float f32x4 __attribute__((ext_vector_type(4)));
typedef unsigned int uint4v __attribute__((ext_vector_type(4)));
typedef unsigned short ushort8 __attribute__((ext_vector_type(8)));

__device__ __forceinline__ ushort f2bf_rne(float f) {
  unsigned u = __float_as_uint(f);
  u += 0x7FFF + ((u >> 16) & 1);
  return (ushort)(u >> 16);
}

// Prep A: cadjs[b,n] = mean_c x[b,c,n] * log2(e)   (pre-scaled for exp2)
__global__ __launch_bounds__(256) void prep_cadj(const float* __restrict__ x,
                                                 float* __restrict__ cadjs) {
  int idx = blockIdx.x * 256 + threadIdx.x;   // 0 .. B*N-1
  int b = idx >> 12;
  int n = idx & (N_DIM - 1);
  const float* p = x + (size_t)b * C_DIM * N_DIM + n;
  float s = 0.f;
#pragma unroll
  for (int c = 0; c < C_DIM; ++c) s += p[(size_t)c * N_DIM];
  cadjs[idx] = s * (1.44269504f / C_DIM);
}

// Prep B: feabT tiled bf16: feabT[((b*128 + n/32)*32 + c)*32 + n%32]
__global__ __launch_bounds__(256) void prep_feab(const float* __restrict__ x,
                                                 ushort* __restrict__ feabT) {
  int idx = blockIdx.x * 256 + threadIdx.x;   // 0 .. 8*32*256-1
  int g = idx & 255;           // n-group of 16
  int c = (idx >> 8) & 31;
  int b = idx >> 13;
  int n0 = g * 16;
  const float* p = x + ((size_t)(b * C_DIM + c)) * N_DIM + n0;
  ushort* q = feabT + ((size_t)(b * (N_DIM / 32) + (n0 >> 5)) * C_DIM + c) * 32 + (n0 & 31);
  ushort8 v0, v1;
#pragma unroll
  for (int j = 0; j < 8; ++j) v0[j] = f2bf_rne(p[j]);
#pragma unroll
  for (int j = 0; j < 8; ++j) v1[j] = f2bf_rne(p[8 + j]);
  *(ushort8*)q = v0;
  *(ushort8*)(q + 8) = v1;
}

// Fused kernel: block = 16 waves (1024 thr); wave wv = K-slice [wv*256,+256),
// all 8 batches (adj fragment amortized 8x, adj read once chip-wide), 16 cols.
// 16 waves/CU = 4 waves/SIMD -- 2x r9's TLP with identical per-wave mix.
// Simple r6-style body (compiler schedules best). LDS reduce over 16 waves in
// 4 passes of 2 batches (64 KB, 2-way=free bank patterns) + fused para*relu.
__global__ __launch_bounds__(1024, 4) void gcn_fused(
    const ushort* __restrict__ feabT, const float* __restrict__ adj,
    const float* __restrict__ cadjs, const float* __restrict__ para,
    float* __restrict__ out) {
  __shared__ float red[NWAVE][1024];   // 64 KB

  const int tid = threadIdx.x;
  const int lane = tid & 63;
  const int wv = tid >> 6;          // 0..15 = K-slice
  const int quad = lane >> 4;
  const int l15 = lane & 15;
  const int colgrp = blockIdx.x;    // 0..255
  const int col = colgrp * 16 + l15;
  const int ksbase = wv * KSL;

  float cm[B_DIM];
#pragma unroll
  for (int b = 0; b < B_DIM; ++b) cm[b] = cadjs[b * N_DIM + col];

  f32x4 acc[B_DIM][2];
#pragma unroll
  for (int b = 0; b < B_DIM; ++b) {
    acc[b][0] = (f32x4){0.f, 0.f, 0.f, 0.f};
    acc[b][1] = (f32x4){0.f, 0.f, 0.f, 0.f};
  }

  float a2[2][8];   // 2*adj, double-buffered across chunks

#define ADJ_STAGE(ch, s)                                                      \
  {                                                                           \
    const int kr = ksbase + (ch) * 32 + quad * 8;                             \
    _Pragma("unroll")                                                         \
    for (int j = 0; j < 8; ++j)                                               \
      a2[s][j] = 2.0f * adj[(size_t)(kr + j) * N_DIM + col];                  \
  }

  ADJ_STAGE(0, 0)

#pragma unroll
  for (int ch = 0; ch < NCH; ++ch) {
    const int s = ch & 1;
    if (ch + 1 < NCH) ADJ_STAGE(ch + 1, s ^ 1)

    const int kb = ksbase + ch * 32;
    const ushort* tilebase = feabT + (size_t)(kb >> 5) * (C_DIM * 32);

#pragma unroll
    for (int b = 0; b < B_DIM; ++b) {
      const ushort* tile = tilebase + (size_t)b * (N_DIM / 32) * (C_DIM * 32);
      const bf16x8 fa0 = *(const bf16x8*)(tile + l15 * 32 + quad * 8);
      const bf16x8 fa1 = *(const bf16x8*)(tile + (16 + l15) * 32 + quad * 8);
      float ckv[8];
      *(f32x4*)&ckv[0] = *(const f32x4*)(cadjs + (size_t)b * N_DIM + kb + quad * 8);
      *(f32x4*)&ckv[4] = *(const f32x4*)(cadjs + (size_t)b * N_DIM + kb + quad * 8 + 4);

      // w = 2*adj / (1 + exp2(|ck' - cm'|)), inputs pre-scaled by log2(e)
      uint4v wfu;
#pragma unroll
      for (int p = 0; p < 4; ++p) {
        float d0 = ckv[2 * p] - cm[b];
        float e0 = __builtin_amdgcn_exp2f(fabsf(d0));
        float w0 = a2[s][2 * p] * __builtin_amdgcn_rcpf(1.0f + e0);
        float d1 = ckv[2 * p + 1] - cm[b];
        float e1 = __builtin_amdgcn_exp2f(fabsf(d1));
        float w1 = a2[s][2 * p + 1] * __builtin_amdgcn_rcpf(1.0f + e1);
        // truncating bf16x2 pack: bytes [w0.b2, w0.b3, w1.b2, w1.b3]
        wfu[p] = __builtin_amdgcn_perm(__float_as_uint(w1), __float_as_uint(w0),
                                       0x07060302u);
      }
      const bf16x8 wf = __builtin_bit_cast(bf16x8, wfu);

      acc[b][0] = __builtin_amdgcn_mfma_f32_16x16x32_bf16(fa0, wf, acc[b][0], 0, 0, 0);
      acc[b][1] = __builtin_amdgcn_mfma_f32_16x16x32_bf16(fa1, wf, acc[b][1], 0, 0, 0);
    }
  }

  // epilogue constants for this thread's fixed (c, col16) slot
  const int ec = (tid & 511) >> 4;
  const int ecol16 = tid & 15;
  const float pv = para[(size_t)ec * N_DIM + colgrp * 16 + ecol16];

  // cross-wave reduction: 4 passes x 2 batches (red = 64 KB)
#pragma unroll
  for (int pass = 0; pass < 4; ++pass) {
    if (pass) __syncthreads();   // previous pass reads done before overwrite
#pragma unroll
    for (int bl = 0; bl < 2; ++bl) {
      const int b = pass * 2 + bl;
#pragma unroll
      for (int h = 0; h < 2; ++h)
#pragma unroll
        for (int r = 0; r < 4; ++r)
          red[wv][bl * 512 + (h * 16 + quad * 4 + r) * 16 + l15] = acc[b][h][r];
    }
    __syncthreads();
    // 1024 outputs per pass: thread t -> (batch pass*2 + (t>>9), c=(t&511)>>4, col16=t&15)
    float ssum = 0.f;
#pragma unroll
    for (int w = 0; w < NWAVE; ++w) ssum += red[w][tid];
    const int b = pass * 2 + (tid >> 9);
    out[((size_t)(b * C_DIM + ec)) * N_DIM + colgrp * 16 + ecol16] =
        fmaxf(ssum * pv, 0.f);
  }
}

extern "C" void kernel_launch(void* const* d_in, const int* in_sizes, int n_in,
                              void* d_out, int out_size, void* d_ws, size_t ws_size,
                              hipStream_t stream) {
  const float* x = (const float*)d_in[0];     // [8,32,64,64]
  const float* para = (const float*)d_in[1];  // [1,32,64,64]
  const float* adj = (const float*)d_in[2];   // [4096,4096]
  float* out = (float*)d_out;

  // ws: cadjs (128 KB) | feabT (2 MB)  -- total 2.25 MB
  float* cadjs = (float*)d_ws;
  ushort* feabT = (ushort*)((char*)d_ws + (size_t)B_DIM * N_DIM * 4);

  prep_cadj<<<dim3(B_DIM * N_DIM / 256), dim3(256), 0, stream>>>(x, cadjs);
  prep_feab<<<dim3(B_DIM * C_DIM * (N_DIM / 16) / 256), dim3(256), 0, stream>>>(x, feabT);
  gcn_fused<<<dim3(N_DIM / 16), dim3(1024), 0, stream>>>(feabT, adj, cadjs, para, out);
}